// Round 1
// baseline (229.233 us; speedup 1.0000x reference)
//
#include <hip/hip_runtime.h>

typedef __attribute__((ext_vector_type(8))) short short8;     // 8 bf16 (guide §3: compile-verified operand type)
typedef __attribute__((ext_vector_type(4))) short short4v;    // 4 bf16
typedef __attribute__((ext_vector_type(4))) float f32x4;
typedef __attribute__((ext_vector_type(8))) unsigned short ushort8;

// B=2, T=2048, D_IN=1024, H=16, D_HEAD=64, D_INNER=1024, M=B*T=4096

__device__ __forceinline__ unsigned short f2bf(float f) {
  union { float f; unsigned int u; } x; x.f = f;
  unsigned int r = x.u + 0x7FFFu + ((x.u >> 16) & 1u);   // RNE
  return (unsigned short)(r >> 16);
}

__device__ __forceinline__ void gload_lds16(const void* g, void* l) {
  __builtin_amdgcn_global_load_lds(
      (const __attribute__((address_space(1))) void*)g,
      (__attribute__((address_space(3))) void*)l, 16, 0, 0);
}

// ---------------- prep kernels ----------------

__global__ void cvt_bf16(const float* __restrict__ src, unsigned short* __restrict__ dst, int n) {
  int i = (blockIdx.x * blockDim.x + threadIdx.x) * 4;
  if (i < n) {
    float4 f = *(const float4*)(src + i);
    ushort4 o;
    o.x = f2bf(f.x); o.y = f2bf(f.y); o.z = f2bf(f.z); o.w = f2bf(f.w);
    *(ushort4*)(dst + i) = o;
  }
}

// dst[n][k] = (bf16) src[k][n]
__global__ void transpose_cvt(const float* __restrict__ src, unsigned short* __restrict__ dst,
                              int K, int N) {
  __shared__ float tile[32][33];
  int kx = blockIdx.x * 32, ny = blockIdx.y * 32;
  int tx = threadIdx.x & 31, ty = threadIdx.x >> 5;  // 32x8
  #pragma unroll
  for (int r = 0; r < 32; r += 8)
    tile[ty + r][tx] = src[(size_t)(kx + ty + r) * N + ny + tx];
  __syncthreads();
  #pragma unroll
  for (int r = 0; r < 32; r += 8)
    dst[(size_t)(ny + ty + r) * K + kx + tx] = f2bf(tile[tx][ty + r]);
}

// ---------------- QKV projection GEMM (m97 structure) ----------------
// C[m][n] = sum_k A[m][k]*W[k][n], A bf16 [4096][1024], Bt = W^T bf16 [1024][1024]
// out layout: [b][h][t][d] bf16; z selects q/k/v; q pre-scaled by 1/32.

__global__ __launch_bounds__(256) void qkv_gemm(
    const unsigned short* __restrict__ A,
    const unsigned short* __restrict__ Bq, const unsigned short* __restrict__ Bk,
    const unsigned short* __restrict__ Bv,
    unsigned short* __restrict__ Oq, unsigned short* __restrict__ Ok,
    unsigned short* __restrict__ Ov) {
  constexpr int Kd = 1024;
  __shared__ __align__(16) unsigned short As[128 * 32];
  __shared__ __align__(16) unsigned short Bs[128 * 32];
  int z = blockIdx.z;
  const unsigned short* Bt = (z == 0) ? Bq : (z == 1) ? Bk : Bv;
  unsigned short* O = (z == 0) ? Oq : (z == 1) ? Ok : Ov;
  float scale = (z == 0) ? 0.03125f : 1.0f;  // 1/sqrt(1024) folded into Q
  int m0 = blockIdx.x * 128, n0 = blockIdx.y * 128;
  int tid = threadIdx.x, lane = tid & 63, wave = tid >> 6;
  int wm = wave >> 1, wn = wave & 1;
  int l15 = lane & 15, quad = lane >> 4;

  f32x4 acc[4][4] = {};

  for (int k0 = 0; k0 < Kd; k0 += 32) {
    __syncthreads();
    #pragma unroll
    for (int r = 0; r < 2; ++r) {
      int i = tid + 256 * r;
      int row = i >> 2, c8 = (i & 3) * 8;
      gload_lds16(A + (size_t)(m0 + row) * Kd + k0 + c8, &As[i * 8]);
    }
    #pragma unroll
    for (int r = 0; r < 2; ++r) {
      int i = tid + 256 * r;
      int row = i >> 2, c8 = (i & 3) * 8;
      gload_lds16(Bt + (size_t)(n0 + row) * Kd + k0 + c8, &Bs[i * 8]);
    }
    __syncthreads();
    short8 af[4], bf[4];
    #pragma unroll
    for (int i = 0; i < 4; ++i)
      af[i] = *(const short8*)&As[(wm * 64 + i * 16 + l15) * 32 + quad * 8];
    #pragma unroll
    for (int j = 0; j < 4; ++j)
      bf[j] = *(const short8*)&Bs[(wn * 64 + j * 16 + l15) * 32 + quad * 8];
    #pragma unroll
    for (int i = 0; i < 4; ++i)
      #pragma unroll
      for (int j = 0; j < 4; ++j)
        acc[i][j] = __builtin_amdgcn_mfma_f32_16x16x32_bf16(af[i], bf[j], acc[i][j], 0, 0, 0);
  }

  #pragma unroll
  for (int i = 0; i < 4; ++i) {
    int mbase = m0 + wm * 64 + i * 16 + quad * 4;
    #pragma unroll
    for (int j = 0; j < 4; ++j) {
      int n = n0 + wn * 64 + j * 16 + l15;
      int h = n >> 6, d = n & 63;
      #pragma unroll
      for (int r = 0; r < 4; ++r) {
        int mm = mbase + r;
        int b = mm >> 11, t = mm & 2047;
        size_t off = (((size_t)(b * 16 + h) * 2048 + t) << 6) + d;
        O[off] = f2bf(acc[i][j][r] * scale);
      }
    }
  }
}

// ---------------- fused causal flash attention ----------------
// grid (T/128, B*H); 4 waves, 32 q-rows each; 64-token K/V tiles.
// Computes S^T = K·Q^T so softmax dim = C-layout rows; P round-trips LDS
// (ds_write_b64) into A-layout; Vs stored transposed+XOR-swizzled.

__global__ __launch_bounds__(256) void attn(
    const unsigned short* __restrict__ Qg, const unsigned short* __restrict__ Kg,
    const unsigned short* __restrict__ Vg, unsigned short* __restrict__ Yg) {
  constexpr int T = 2048;
  __shared__ __align__(16) unsigned short Ks[64 * 64];
  __shared__ __align__(16) unsigned short Vs[64 * 64];
  __shared__ __align__(16) unsigned short Ps[4][32 * 64];
  int bh = blockIdx.y;
  int q0 = blockIdx.x * 128;
  int tid = threadIdx.x, lane = tid & 63, wave = tid >> 6;
  int l15 = lane & 15, quad = lane >> 4;
  const unsigned short* Qb = Qg + (size_t)bh * T * 64;
  const unsigned short* Kb = Kg + (size_t)bh * T * 64;
  const unsigned short* Vb = Vg + (size_t)bh * T * 64;
  int qw = q0 + wave * 32;

  // Q as B-operand frags: B[k=d][n=q] -> Q[q][d], 16B global loads, held in regs
  short8 qfrag[2][2];
  #pragma unroll
  for (int jq = 0; jq < 2; ++jq)
    #pragma unroll
    for (int s = 0; s < 2; ++s)
      qfrag[jq][s] = *(const short8*)(Qb + (size_t)(qw + jq * 16 + l15) * 64 + quad * 8 + 32 * s);

  f32x4 Oacc[2][4] = {};
  float m_run[2] = {-__builtin_inff(), -__builtin_inff()};
  float l_run[2] = {0.f, 0.f};

  int nkt = (q0 + 128) >> 6;  // causal trip count
  for (int kt = 0; kt < nkt; ++kt) {
    const unsigned short* Kt = Kb + kt * 64 * 64;
    const unsigned short* Vt = Vb + kt * 64 * 64;
    __syncthreads();
    // stage K: [tok][d ^ ((tok&7)<<3)]  (swizzle keeps 8-blocks contiguous, bank-floor)
    #pragma unroll
    for (int r = 0; r < 2; ++r) {
      int i = tid + 256 * r;
      int tok = i >> 3, d0 = (i & 7) * 8;
      ushort8 v = *(const ushort8*)(Kt + tok * 64 + d0);
      *(ushort8*)&Ks[tok * 64 + (d0 ^ ((tok & 7) << 3))] = v;
    }
    // stage V transposed: Vs[d][tok ^ ((d>>3)<<3)]
    #pragma unroll
    for (int r = 0; r < 2; ++r) {
      int i = tid + 256 * r;
      int tok = i >> 3, d0 = (i & 7) * 8;
      ushort8 v = *(const ushort8*)(Vt + tok * 64 + d0);
      int t2 = tok ^ d0;  // ((d0+j)>>3)<<3 == d0
      #pragma unroll
      for (int j = 0; j < 8; ++j)
        Vs[(d0 + j) * 64 + t2] = ((const unsigned short*)&v)[j];
    }
    __syncthreads();

    // S^T = K·Q^T : rows=tok, cols=q
    f32x4 Sacc[4][2] = {};
    #pragma unroll
    for (int s = 0; s < 2; ++s) {
      #pragma unroll
      for (int mi = 0; mi < 4; ++mi) {
        int tokr = mi * 16 + l15;
        short8 kf = *(const short8*)&Ks[tokr * 64 + ((quad * 8 + 32 * s) ^ ((tokr & 7) << 3))];
        #pragma unroll
        for (int jq = 0; jq < 2; ++jq)
          Sacc[mi][jq] = __builtin_amdgcn_mfma_f32_16x16x32_bf16(kf, qfrag[jq][s], Sacc[mi][jq], 0, 0, 0);
      }
    }

    // causal mask: tok > q -> -inf
    if (kt * 64 + 63 > qw) {
      #pragma unroll
      for (int mi = 0; mi < 4; ++mi) {
        int tok = kt * 64 + mi * 16 + quad * 4;
        #pragma unroll
        for (int jq = 0; jq < 2; ++jq) {
          int q = qw + jq * 16 + l15;
          #pragma unroll
          for (int r = 0; r < 4; ++r)
            if (tok + r > q) Sacc[mi][jq][r] = -__builtin_inff();
        }
      }
    }

    // online softmax along tok (C-rows): lane-local max + shfl_xor 16,32
    float alpha[2];
    #pragma unroll
    for (int jq = 0; jq < 2; ++jq) {
      float vmax = -__builtin_inff();
      #pragma unroll
      for (int mi = 0; mi < 4; ++mi)
        #pragma unroll
        for (int r = 0; r < 4; ++r)
          vmax = fmaxf(vmax, Sacc[mi][jq][r]);
      vmax = fmaxf(vmax, __shfl_xor(vmax, 16));
      vmax = fmaxf(vmax, __shfl_xor(vmax, 32));
      float mnew = fmaxf(m_run[jq], vmax);
      alpha[jq] = __expf(m_run[jq] - mnew);
      m_run[jq] = mnew;
      float rs = 0.f;
      int qcol = jq * 16 + l15;
      int swz = (qcol & 7) << 3;
      #pragma unroll
      for (int mi = 0; mi < 4; ++mi) {
        float p0 = __expf(Sacc[mi][jq][0] - mnew);
        float p1 = __expf(Sacc[mi][jq][1] - mnew);
        float p2 = __expf(Sacc[mi][jq][2] - mnew);
        float p3 = __expf(Sacc[mi][jq][3] - mnew);
        rs += (p0 + p1) + (p2 + p3);
        short4v pk;
        pk[0] = (short)f2bf(p0); pk[1] = (short)f2bf(p1);
        pk[2] = (short)f2bf(p2); pk[3] = (short)f2bf(p3);
        *(short4v*)&Ps[wave][qcol * 64 + ((mi * 16 + quad * 4) ^ swz)] = pk;
      }
      rs += __shfl_xor(rs, 16);
      rs += __shfl_xor(rs, 32);
      l_run[jq] = l_run[jq] * alpha[jq] + rs;
    }

    // rescale O rows (alpha is col-indexed -> redistribute via shfl)
    #pragma unroll
    for (int mq = 0; mq < 2; ++mq)
      #pragma unroll
      for (int r = 0; r < 4; ++r) {
        float a = __shfl(alpha[mq], quad * 4 + r);
        #pragma unroll
        for (int jd = 0; jd < 4; ++jd)
          Oacc[mq][jd][r] *= a;
      }

    // O += P·V
    #pragma unroll
    for (int s = 0; s < 2; ++s) {
      short8 pf[2];
      #pragma unroll
      for (int mq = 0; mq < 2; ++mq) {
        int ql = mq * 16 + l15;
        pf[mq] = *(const short8*)&Ps[wave][ql * 64 + ((quad * 8 + 32 * s) ^ ((ql & 7) << 3))];
      }
      #pragma unroll
      for (int jd = 0; jd < 4; ++jd) {
        int dd = jd * 16 + l15;
        short8 vf = *(const short8*)&Vs[dd * 64 + ((quad * 8 + 32 * s) ^ ((dd >> 3) << 3))];
        #pragma unroll
        for (int mq = 0; mq < 2; ++mq)
          Oacc[mq][jd] = __builtin_amdgcn_mfma_f32_16x16x32_bf16(pf[mq], vf, Oacc[mq][jd], 0, 0, 0);
      }
    }
  }

  // finalize: O/l, write Y [b*T+q][h*64+d] bf16
  int h = bh & 15, b = bh >> 4;
  #pragma unroll
  for (int mq = 0; mq < 2; ++mq)
    #pragma unroll
    for (int r = 0; r < 4; ++r) {
      float linv = 1.f / __shfl(l_run[mq], quad * 4 + r);
      int q = qw + mq * 16 + quad * 4 + r;
      size_t row = (size_t)(b * 2048 + q) * 1024 + h * 64;
      #pragma unroll
      for (int jd = 0; jd < 4; ++jd)
        Yg[row + jd * 16 + l15] = f2bf(Oacc[mq][jd][r] * linv);
    }
}

// ---------------- out projection: Y[4096x1024]·Wo[1024x64] + bo -> fp32 ----------------

__global__ __launch_bounds__(256) void oproj(
    const unsigned short* __restrict__ Y, const unsigned short* __restrict__ Wot,
    const float* __restrict__ bo, float* __restrict__ out) {
  __shared__ __align__(16) unsigned short As[64 * 32];
  __shared__ __align__(16) unsigned short Bs[64 * 32];
  int m0 = blockIdx.x * 64;
  int tid = threadIdx.x, lane = tid & 63, wave = tid >> 6;
  int l15 = lane & 15, quad = lane >> 4;
  f32x4 acc[4] = {};
  for (int k0 = 0; k0 < 1024; k0 += 32) {
    __syncthreads();
    {
      int row = tid >> 2, c8 = (tid & 3) * 8;
      gload_lds16(Y + (size_t)(m0 + row) * 1024 + k0 + c8, &As[tid * 8]);
      gload_lds16(Wot + (size_t)row * 1024 + k0 + c8, &Bs[tid * 8]);
    }
    __syncthreads();
    short8 af = *(const short8*)&As[(wave * 16 + l15) * 32 + quad * 8];
    #pragma unroll
    for (int j = 0; j < 4; ++j) {
      short8 bf = *(const short8*)&Bs[(j * 16 + l15) * 32 + quad * 8];
      acc[j] = __builtin_amdgcn_mfma_f32_16x16x32_bf16(af, bf, acc[j], 0, 0, 0);
    }
  }
  #pragma unroll
  for (int j = 0; j < 4; ++j) {
    int n = j * 16 + l15;
    float bias = bo[n];
    #pragma unroll
    for (int r = 0; r < 4; ++r) {
      int m = m0 + wave * 16 + quad * 4 + r;
      out[(size_t)m * 64 + n] = acc[j][r] + bias;
    }
  }
}

// ---------------- launcher ----------------

extern "C" void kernel_launch(void* const* d_in, const int* in_sizes, int n_in,
                              void* d_out, int out_size, void* d_ws, size_t ws_size,
                              hipStream_t stream) {
  const float* x  = (const float*)d_in[0];
  const float* Wq = (const float*)d_in[1];
  const float* Wk = (const float*)d_in[2];
  const float* Wv = (const float*)d_in[3];
  const float* Wo = (const float*)d_in[4];
  const float* bo = (const float*)d_in[5];
  float* out = (float*)d_out;
  char* ws = (char*)d_ws;

  unsigned short* xb  = (unsigned short*)(ws);                       // 8 MB  [4096][1024]
  unsigned short* wqt = (unsigned short*)(ws + (8ull << 20));        // 2 MB  [1024][1024] = Wq^T
  unsigned short* wkt = (unsigned short*)(ws + (10ull << 20));       // 2 MB
  unsigned short* wvt = (unsigned short*)(ws + (12ull << 20));       // 2 MB
  unsigned short* wot = (unsigned short*)(ws + (14ull << 20));       // 128 KB [64][1024] = Wo^T
  unsigned short* q   = (unsigned short*)(ws + (15ull << 20));       // 8 MB  [b][h][t][d]
  unsigned short* k   = (unsigned short*)(ws + (23ull << 20));       // 8 MB
  unsigned short* v   = (unsigned short*)(ws + (31ull << 20));       // 8 MB
  unsigned short* y   = (unsigned short*)(ws + (39ull << 20));       // 8 MB  [4096][1024]

  cvt_bf16<<<4096, 256, 0, stream>>>(x, xb, 4096 * 1024);
  transpose_cvt<<<dim3(32, 32), 256, 0, stream>>>(Wq, wqt, 1024, 1024);
  transpose_cvt<<<dim3(32, 32), 256, 0, stream>>>(Wk, wkt, 1024, 1024);
  transpose_cvt<<<dim3(32, 32), 256, 0, stream>>>(Wv, wvt, 1024, 1024);
  transpose_cvt<<<dim3(32, 2),  256, 0, stream>>>(Wo, wot, 1024, 64);
  qkv_gemm<<<dim3(32, 8, 3), 256, 0, stream>>>(xb, wqt, wkt, wvt, q, k, v);
  attn<<<dim3(16, 32), 256, 0, stream>>>(q, k, v, y);
  oproj<<<64, 256, 0, stream>>>(y, wot, bo, out);
}

// Round 2
// 193.817 us; speedup vs baseline: 1.1827x; 1.1827x over previous
//
#include <hip/hip_runtime.h>

typedef __attribute__((ext_vector_type(8))) short short8;     // 8 bf16 MFMA operand
typedef __attribute__((ext_vector_type(4))) float f32x4;
typedef __attribute__((ext_vector_type(8))) unsigned short ushort8v;

// B=2, T=2048, D_IN=1024, H=16, D_HEAD=64, D_INNER=1024, M=B*T=4096

__device__ __forceinline__ unsigned short f2bf(float f) {
  union { float f; unsigned int u; } x; x.f = f;
  unsigned int r = x.u + 0x7FFFu + ((x.u >> 16) & 1u);   // RNE
  return (unsigned short)(r >> 16);
}

__device__ __forceinline__ void gload_lds16(const void* g, void* l) {
  __builtin_amdgcn_global_load_lds(
      (const __attribute__((address_space(1))) void*)g,
      (__attribute__((address_space(3))) void*)l, 16, 0, 0);
}

// ---------------- prep kernels ----------------

__global__ void cvt_bf16(const float* __restrict__ src, unsigned short* __restrict__ dst, int n) {
  int i = (blockIdx.x * blockDim.x + threadIdx.x) * 4;
  if (i < n) {
    float4 f = *(const float4*)(src + i);
    ushort4 o;
    o.x = f2bf(f.x); o.y = f2bf(f.y); o.z = f2bf(f.z); o.w = f2bf(f.w);
    *(ushort4*)(dst + i) = o;
  }
}

// dst[n][k] = (bf16) src[k][n]
__global__ void transpose_cvt(const float* __restrict__ src, unsigned short* __restrict__ dst,
                              int K, int N) {
  __shared__ float tile[32][33];
  int kx = blockIdx.x * 32, ny = blockIdx.y * 32;
  int tx = threadIdx.x & 31, ty = threadIdx.x >> 5;  // 32x8
  #pragma unroll
  for (int r = 0; r < 32; r += 8)
    tile[ty + r][tx] = src[(size_t)(kx + ty + r) * N + ny + tx];
  __syncthreads();
  #pragma unroll
  for (int r = 0; r < 32; r += 8)
    dst[(size_t)(ny + ty + r) * K + kx + tx] = f2bf(tile[tx][ty + r]);
}

// ---------------- QKV projection GEMM (m97 structure) ----------------
// z=0: Q = x·Wq scaled by 1/32, layout [b][h][t][d]
// z=1: K = x·Wk,               layout [b][h][t][d]
// z=2: V^T computed directly (A=Wv^T, B=x -> D[d_inner][t]), layout [b][h][d][t]

__global__ __launch_bounds__(256) void qkv_gemm(
    const unsigned short* __restrict__ Xb,
    const unsigned short* __restrict__ Wqt, const unsigned short* __restrict__ Wkt,
    const unsigned short* __restrict__ Wvt,
    unsigned short* __restrict__ Oq, unsigned short* __restrict__ Ok,
    unsigned short* __restrict__ Ovt) {
  constexpr int Kd = 1024;
  __shared__ __align__(16) unsigned short As[128 * 32];
  __shared__ __align__(16) unsigned short Bs[128 * 32];
  int z = blockIdx.z;
  int m0, n0;
  const unsigned short *Arow, *Brow;
  if (z == 2) {  // m over d_inner (1024), n over tokens (4096)
    m0 = blockIdx.y * 128; n0 = blockIdx.x * 128;
    Arow = Wvt; Brow = Xb;
  } else {
    m0 = blockIdx.x * 128; n0 = blockIdx.y * 128;
    Arow = Xb; Brow = (z == 0) ? Wqt : Wkt;
  }
  int tid = threadIdx.x, lane = tid & 63, wave = tid >> 6;
  int wm = wave >> 1, wn = wave & 1;
  int l15 = lane & 15, quad = lane >> 4;

  f32x4 acc[4][4] = {};

  for (int k0 = 0; k0 < Kd; k0 += 32) {
    __syncthreads();
    #pragma unroll
    for (int r = 0; r < 2; ++r) {
      int i = tid + 256 * r;
      int row = i >> 2, c8 = (i & 3) * 8;
      gload_lds16(Arow + (size_t)(m0 + row) * Kd + k0 + c8, &As[i * 8]);
    }
    #pragma unroll
    for (int r = 0; r < 2; ++r) {
      int i = tid + 256 * r;
      int row = i >> 2, c8 = (i & 3) * 8;
      gload_lds16(Brow + (size_t)(n0 + row) * Kd + k0 + c8, &Bs[i * 8]);
    }
    __syncthreads();
    short8 af[4], bf[4];
    #pragma unroll
    for (int i = 0; i < 4; ++i)
      af[i] = *(const short8*)&As[(wm * 64 + i * 16 + l15) * 32 + quad * 8];
    #pragma unroll
    for (int j = 0; j < 4; ++j)
      bf[j] = *(const short8*)&Bs[(wn * 64 + j * 16 + l15) * 32 + quad * 8];
    #pragma unroll
    for (int i = 0; i < 4; ++i)
      #pragma unroll
      for (int j = 0; j < 4; ++j)
        acc[i][j] = __builtin_amdgcn_mfma_f32_16x16x32_bf16(af[i], bf[j], acc[i][j], 0, 0, 0);
  }

  if (z == 2) {
    // D[m=d_inner][n=token] -> Vt[(b*16+h)*64 + d][t]
    #pragma unroll
    for (int i = 0; i < 4; ++i) {
      int dmbase = m0 + wm * 64 + i * 16 + quad * 4;
      #pragma unroll
      for (int j = 0; j < 4; ++j) {
        int tn = n0 + wn * 64 + j * 16 + l15;
        int b = tn >> 11, t = tn & 2047;
        #pragma unroll
        for (int r = 0; r < 4; ++r) {
          int dm = dmbase + r;
          int h = dm >> 6, d = dm & 63;
          Ovt[(((size_t)(b * 16 + h) * 64 + d) << 11) + t] = f2bf(acc[i][j][r]);
        }
      }
    }
  } else {
    unsigned short* O = (z == 0) ? Oq : Ok;
    float scale = (z == 0) ? 0.03125f : 1.0f;  // 1/sqrt(1024) folded into Q
    #pragma unroll
    for (int i = 0; i < 4; ++i) {
      int mbase = m0 + wm * 64 + i * 16 + quad * 4;
      #pragma unroll
      for (int j = 0; j < 4; ++j) {
        int n = n0 + wn * 64 + j * 16 + l15;
        int h = n >> 6, d = n & 63;
        #pragma unroll
        for (int r = 0; r < 4; ++r) {
          int mm = mbase + r;
          int b = mm >> 11, t = mm & 2047;
          size_t off = (((size_t)(b * 16 + h) * 2048 + t) << 6) + d;
          O[off] = f2bf(acc[i][j][r] * scale);
        }
      }
    }
  }
}

// ---------------- fused causal flash attention v2 ----------------
// grid (32, 32): 64-row q-tiles, qt=(bx+by)&31 work swizzle for balance.
// 4 waves/block, 16 q-rows/wave. 64-token K/V tiles, pad-72 LDS rows
// (bank-floor for all b128/b64 accesses), software-pipelined staging.

__global__ __launch_bounds__(256, 4) void attn2(
    const unsigned short* __restrict__ Qg, const unsigned short* __restrict__ Kg,
    const unsigned short* __restrict__ Vtg, unsigned short* __restrict__ Yg) {
  constexpr int T = 2048;
  __shared__ __align__(16) unsigned short Ks[64 * 72];
  __shared__ __align__(16) unsigned short Vs[64 * 72];
  __shared__ __align__(16) unsigned short Ps[4][16 * 72];
  int bh = blockIdx.y;
  int qt = (blockIdx.x + blockIdx.y) & 31;
  int q0 = qt * 64;
  int tid = threadIdx.x, lane = tid & 63, wave = tid >> 6;
  int l15 = lane & 15, quad = lane >> 4;
  const unsigned short* Qb = Qg + (size_t)bh * T * 64;
  const unsigned short* Kb = Kg + (size_t)bh * T * 64;
  const unsigned short* Vb = Vtg + (size_t)bh * 64 * T;
  int qw = q0 + wave * 16;

  // Q as B-operand frags (held in regs): B[k=d][n=q] from Q[q][d]
  short8 qf[2];
  #pragma unroll
  for (int s = 0; s < 2; ++s)
    qf[s] = *(const short8*)(Qb + (size_t)(qw + l15) * 64 + quad * 8 + 32 * s);

  f32x4 Oacc[4] = {};
  float m_run = -__builtin_inff(), l_run = 0.f;

  // prefetch tile 0
  ushort8v kpre[2], vpre[2];
  #pragma unroll
  for (int r = 0; r < 2; ++r) {
    int i = tid + 256 * r;
    kpre[r] = *(const ushort8v*)(Kb + (size_t)(i >> 3) * 64 + (i & 7) * 8);
    vpre[r] = *(const ushort8v*)(Vb + (size_t)(i >> 3) * T + (i & 7) * 8);
  }

  for (int kt = 0; kt <= qt; ++kt) {
    __syncthreads();
    #pragma unroll
    for (int r = 0; r < 2; ++r) {
      int i = tid + 256 * r;
      *(ushort8v*)&Ks[(i >> 3) * 72 + (i & 7) * 8] = kpre[r];
      *(ushort8v*)&Vs[(i >> 3) * 72 + (i & 7) * 8] = vpre[r];
    }
    __syncthreads();
    if (kt < qt) {  // prefetch next tile while computing
      #pragma unroll
      for (int r = 0; r < 2; ++r) {
        int i = tid + 256 * r;
        kpre[r] = *(const ushort8v*)(Kb + (size_t)((kt + 1) * 64 + (i >> 3)) * 64 + (i & 7) * 8);
        vpre[r] = *(const ushort8v*)(Vb + (size_t)(i >> 3) * T + (kt + 1) * 64 + (i & 7) * 8);
      }
    }

    // S^T = K·Q^T : rows=tok(64), cols=q(16)
    f32x4 S[4] = {};
    #pragma unroll
    for (int s = 0; s < 2; ++s)
      #pragma unroll
      for (int mi = 0; mi < 4; ++mi) {
        short8 kf = *(const short8*)&Ks[(mi * 16 + l15) * 72 + quad * 8 + 32 * s];
        S[mi] = __builtin_amdgcn_mfma_f32_16x16x32_bf16(kf, qf[s], S[mi], 0, 0, 0);
      }

    if (kt == qt) {  // diagonal tile: mask tok_local > q_local
      int ql = wave * 16 + l15;
      #pragma unroll
      for (int mi = 0; mi < 4; ++mi) {
        int tokl = mi * 16 + quad * 4;
        #pragma unroll
        for (int r = 0; r < 4; ++r)
          if (tokl + r > ql) S[mi][r] = -__builtin_inff();
      }
    }

    // online softmax along tok (lane-local 16 + quads via shfl_xor 16,32)
    float vmax = -__builtin_inff();
    #pragma unroll
    for (int mi = 0; mi < 4; ++mi)
      #pragma unroll
      for (int r = 0; r < 4; ++r)
        vmax = fmaxf(vmax, S[mi][r]);
    vmax = fmaxf(vmax, __shfl_xor(vmax, 16));
    vmax = fmaxf(vmax, __shfl_xor(vmax, 32));
    float mnew = fmaxf(m_run, vmax);
    float alpha = __expf(m_run - mnew);
    m_run = mnew;
    float rs = 0.f;
    #pragma unroll
    for (int mi = 0; mi < 4; ++mi) {
      float p0 = __expf(S[mi][0] - mnew);
      float p1 = __expf(S[mi][1] - mnew);
      float p2 = __expf(S[mi][2] - mnew);
      float p3 = __expf(S[mi][3] - mnew);
      rs += (p0 + p1) + (p2 + p3);
      // round-half-up pack to 2x bf16 pairs, b64 store (4 consecutive toks)
      union { float f; unsigned int u; } a0{p0}, a1{p1}, a2{p2}, a3{p3};
      uint2 pk;
      pk.x = ((a0.u + 0x8000u) >> 16) | ((a1.u + 0x8000u) & 0xFFFF0000u);
      pk.y = ((a2.u + 0x8000u) >> 16) | ((a3.u + 0x8000u) & 0xFFFF0000u);
      *(uint2*)&Ps[wave][l15 * 72 + mi * 16 + quad * 4] = pk;
    }
    rs += __shfl_xor(rs, 16);
    rs += __shfl_xor(rs, 32);
    l_run = l_run * alpha + rs;

    // rescale O (alpha indexed by q=l15 -> redistribute to C rows quad*4+r)
    #pragma unroll
    for (int r = 0; r < 4; ++r) {
      float a = __shfl(alpha, quad * 4 + r);
      #pragma unroll
      for (int jd = 0; jd < 4; ++jd)
        Oacc[jd][r] *= a;
    }

    // O += P·V  (A=P[q][tok], B=V^T[d][tok])
    #pragma unroll
    for (int s = 0; s < 2; ++s) {
      short8 pf = *(const short8*)&Ps[wave][l15 * 72 + quad * 8 + 32 * s];
      #pragma unroll
      for (int jd = 0; jd < 4; ++jd) {
        short8 vf = *(const short8*)&Vs[(jd * 16 + l15) * 72 + quad * 8 + 32 * s];
        Oacc[jd] = __builtin_amdgcn_mfma_f32_16x16x32_bf16(pf, vf, Oacc[jd], 0, 0, 0);
      }
    }
  }

  // finalize: O/l, write Y [b*T+q][h*64+d] bf16
  int h = bh & 15, b = bh >> 4;
  #pragma unroll
  for (int r = 0; r < 4; ++r) {
    float linv = 1.f / __shfl(l_run, quad * 4 + r);
    int q = qw + quad * 4 + r;
    size_t row = (size_t)(b * 2048 + q) * 1024 + h * 64;
    #pragma unroll
    for (int jd = 0; jd < 4; ++jd)
      Yg[row + jd * 16 + l15] = f2bf(Oacc[jd][r] * linv);
  }
}

// ---------------- out projection ----------------
// out is re-poisoned before every call: seed with bias, then split-K atomics.

__global__ void bias_init(const float* __restrict__ bo, float* __restrict__ out) {
  int t = blockIdx.x * 256 + threadIdx.x;  // 65536 float4s
  float4 b = *(const float4*)(bo + (t & 15) * 4);
  *(float4*)(out + (size_t)t * 4) = b;
}

__global__ __launch_bounds__(256) void oproj(
    const unsigned short* __restrict__ Y, const unsigned short* __restrict__ Wot,
    float* __restrict__ out) {
  __shared__ __align__(16) unsigned short As[64 * 32];
  __shared__ __align__(16) unsigned short Bs[64 * 32];
  int m0 = blockIdx.x * 64;
  int kbase = blockIdx.y * 256;  // 4-way split-K
  int tid = threadIdx.x, lane = tid & 63, wave = tid >> 6;
  int l15 = lane & 15, quad = lane >> 4;
  f32x4 acc[4] = {};
  for (int k0 = kbase; k0 < kbase + 256; k0 += 32) {
    __syncthreads();
    {
      int row = tid >> 2, c8 = (tid & 3) * 8;
      gload_lds16(Y + (size_t)(m0 + row) * 1024 + k0 + c8, &As[tid * 8]);
      gload_lds16(Wot + (size_t)row * 1024 + k0 + c8, &Bs[tid * 8]);
    }
    __syncthreads();
    short8 af = *(const short8*)&As[(wave * 16 + l15) * 32 + quad * 8];
    #pragma unroll
    for (int j = 0; j < 4; ++j) {
      short8 bf = *(const short8*)&Bs[(j * 16 + l15) * 32 + quad * 8];
      acc[j] = __builtin_amdgcn_mfma_f32_16x16x32_bf16(af, bf, acc[j], 0, 0, 0);
    }
  }
  #pragma unroll
  for (int j = 0; j < 4; ++j) {
    int n = j * 16 + l15;
    #pragma unroll
    for (int r = 0; r < 4; ++r) {
      int m = m0 + wave * 16 + quad * 4 + r;
      atomicAdd(&out[(size_t)m * 64 + n], acc[j][r]);
    }
  }
}

// ---------------- launcher ----------------

extern "C" void kernel_launch(void* const* d_in, const int* in_sizes, int n_in,
                              void* d_out, int out_size, void* d_ws, size_t ws_size,
                              hipStream_t stream) {
  const float* x  = (const float*)d_in[0];
  const float* Wq = (const float*)d_in[1];
  const float* Wk = (const float*)d_in[2];
  const float* Wv = (const float*)d_in[3];
  const float* Wo = (const float*)d_in[4];
  const float* bo = (const float*)d_in[5];
  float* out = (float*)d_out;
  char* ws = (char*)d_ws;

  unsigned short* xb  = (unsigned short*)(ws);                       // 8 MB  [4096][1024]
  unsigned short* wqt = (unsigned short*)(ws + (8ull << 20));        // 2 MB  [1024][1024] = Wq^T
  unsigned short* wkt = (unsigned short*)(ws + (10ull << 20));       // 2 MB
  unsigned short* wvt = (unsigned short*)(ws + (12ull << 20));       // 2 MB
  unsigned short* wot = (unsigned short*)(ws + (14ull << 20));       // 128 KB [64][1024] = Wo^T
  unsigned short* q   = (unsigned short*)(ws + (15ull << 20));       // 8 MB  [b][h][t][d]
  unsigned short* k   = (unsigned short*)(ws + (23ull << 20));       // 8 MB  [b][h][t][d]
  unsigned short* vt  = (unsigned short*)(ws + (31ull << 20));       // 8 MB  [b][h][d][t]
  unsigned short* y   = (unsigned short*)(ws + (39ull << 20));       // 8 MB  [4096][1024]

  bias_init<<<256, 256, 0, stream>>>(bo, out);
  cvt_bf16<<<4096, 256, 0, stream>>>(x, xb, 4096 * 1024);
  transpose_cvt<<<dim3(32, 32), 256, 0, stream>>>(Wq, wqt, 1024, 1024);
  transpose_cvt<<<dim3(32, 32), 256, 0, stream>>>(Wk, wkt, 1024, 1024);
  transpose_cvt<<<dim3(32, 32), 256, 0, stream>>>(Wv, wvt, 1024, 1024);
  transpose_cvt<<<dim3(32, 2),  256, 0, stream>>>(Wo, wot, 1024, 64);
  qkv_gemm<<<dim3(32, 8, 3), 256, 0, stream>>>(xb, wqt, wkt, wvt, q, k, vt);
  attn2<<<dim3(32, 32), 256, 0, stream>>>(q, k, vt, y);
  oproj<<<dim3(64, 4), 256, 0, stream>>>(y, wot, out);
}